// Round 7
// baseline (1872.439 us; speedup 1.0000x reference)
//
#include <hip/hip_runtime.h>
#include <hip/hip_fp16.h>
#include <hip/hip_cooperative_groups.h>

namespace cg = cooperative_groups;

typedef unsigned short u16;
typedef unsigned int u32;
typedef __attribute__((ext_vector_type(8))) short short8;
typedef __attribute__((ext_vector_type(4))) float floatx4;

#define EPSI 1e-5f

__device__ __forceinline__ float b2f(u16 h) { return __uint_as_float(((u32)h) << 16); }
__device__ __forceinline__ u16 f2b(float f) {
    u32 u = __float_as_uint(f);
    return (u16)((u + 0x7fffu + ((u >> 16) & 1u)) >> 16);
}
__device__ __forceinline__ u32 pack2(float a, float b) {
    return (u32)f2b(a) | ((u32)f2b(b) << 16);
}
// fm: 0 = f32, 1 = bf16, 2 = f16. Element-indexed, width-agnostic.
__device__ __forceinline__ float ldf(const void* p, int i, int fm) {
    if (fm == 1) return b2f(((const u16*)p)[i]);
    if (fm == 2) return __half2float(__ushort_as_half(((const u16*)p)[i]));
    return ((const float*)p)[i];
}
// im: 0 = int32, 1 = int64 (little-endian low word)
__device__ __forceinline__ int ldi(const void* p, int i, int im) {
    return im ? ((const int*)p)[2 * i] : ((const int*)p)[i];
}

struct MegaParams {
    const void *x, *ei, *batch;
    const void *bn_feat_g, *bn_feat_b, *conv_feat_W, *conv_feat_b;
    const void *conv_W, *conv_b, *bn_conv_g, *bn_conv_b;
    const void *gate_W1, *gate_b1, *gate_W2, *gate_b2;
    const void *fc_W, *fc_b, *bn_fc_g, *bn_fc_b, *cls_W, *cls_b;
    u32* zbase;
    int* flags;
    int* cnt;
    int* fillc;
    float* stats;   // 5 slots x 8 copies x 256
    float* statsP;  // 8 copies x 256 (pool BN)
    int* part;
    int* row_start;
    int* col_idx;
    float* coef;
    int* bnd;
    u16* Wt;
    float* bias2;
    u16* Wtg;
    float* bias2g;
    float* fcWf;
    float* fcbf;
    float* clsWf;
    float* clsbf;
    float* gW2f;
    float* gb2f;
    float* gateb;
    float* pooled;
    u16* A;
    u16* C;
    void* out;
    int nz, N, E, NB;
};

// One 64-row MFMA tile: bf16 A[64,128] @ Wt^T + bias2.
// mode 0: store C (bf16). mode 2: fused gate head -> gate[r] = sigmoid(relu(h)·W2 + b2).
__device__ __forceinline__ void mfma_tile(const u16* __restrict__ A, const u16* __restrict__ Wt,
                                          const float* __restrict__ bias2, u16* __restrict__ C,
                                          float* __restrict__ gate,
                                          const float* __restrict__ gW2f, float gb2, int N,
                                          int mode, int tile, int t) {
    int wid = t >> 6, lane = t & 63;
    int m16 = lane & 15, q = lane >> 4;
    int row0 = tile * 64 + wid * 16;
    if (row0 >= N) return;  // per-wave uniform; no barriers inside
    int arow = row0 + m16;
    floatx4 acc[8];
#pragma unroll
    for (int i = 0; i < 8; ++i) acc[i] = (floatx4){0.f, 0.f, 0.f, 0.f};
#pragma unroll
    for (int kc = 0; kc < 4; ++kc) {
        short8 af;
        if (arow < N) {
            af = *(const short8*)&A[(size_t)arow * 128 + kc * 32 + q * 8];
        } else {
#pragma unroll
            for (int j = 0; j < 8; ++j) af[j] = 0;
        }
#pragma unroll
        for (int nt = 0; nt < 8; ++nt) {
            short8 bf = *(const short8*)&Wt[(nt * 16 + m16) * 128 + kc * 32 + q * 8];
            acc[nt] = __builtin_amdgcn_mfma_f32_16x16x32_bf16(af, bf, acc[nt], 0, 0, 0);
        }
    }
    if (mode == 0) {
#pragma unroll
        for (int nt = 0; nt < 8; ++nt) {
            float b2v = bias2[nt * 16 + m16];
#pragma unroll
            for (int reg = 0; reg < 4; ++reg) {
                int r = row0 + q * 4 + reg;
                if (r < N) C[(size_t)r * 128 + nt * 16 + m16] = f2b(acc[nt][reg] + b2v);
            }
        }
    } else {
        float p[4] = {0.f, 0.f, 0.f, 0.f};
#pragma unroll
        for (int nt = 0; nt < 8; ++nt) {
            float b2v = bias2[nt * 16 + m16];
            float w2v = gW2f[nt * 16 + m16];
#pragma unroll
            for (int reg = 0; reg < 4; ++reg)
                p[reg] += fmaxf(acc[nt][reg] + b2v, 0.0f) * w2v;
        }
#pragma unroll
        for (int reg = 0; reg < 4; ++reg) {
            float v = p[reg];
            v += __shfl_xor(v, 1);
            v += __shfl_xor(v, 2);
            v += __shfl_xor(v, 4);
            v += __shfl_xor(v, 8);
            if (m16 == 0) {
                int r = row0 + q * 4 + reg;
                if (r < N) gate[r] = 1.0f / (1.0f + expf(-(v + gb2)));
            }
        }
    }
}

__global__ __launch_bounds__(256, 4) void mega_kernel(MegaParams p) {
    cg::grid_group grid = cg::this_grid();
    __shared__ int shi[256];
    __shared__ float2 shf2[256];
    __shared__ float red[256];
    __shared__ float scs[128];
    __shared__ float shs[128];
    __shared__ float fco[128];
    __shared__ float lg[10];
    __shared__ float redv[2];

    const int t = threadIdx.x;
    const int bid = blockIdx.x;
    const int nb = gridDim.x;
    const int gid = bid * 256 + t;
    const int gstride = nb * 256;

    // ---- P0: zero workspace counters/stats + dtype detect ----
    for (int i = gid; i < p.nz; i += gstride) p.zbase[i] = 0;
    if (gid == 0) {
        u32 w = ((const u32*)p.bn_feat_g)[0];
        int fmv = 0;
        if (w == 0x3F803F80u) fmv = 1;
        else if (w == 0x3C003C00u) fmv = 2;
        const u32* e = (const u32*)p.ei;
        int all0 = 1;
        for (int k = 0; k < 16; ++k)
            if (e[2 * k + 1] != 0u) all0 = 0;
        p.flags[0] = fmv;
        p.flags[1] = all0;
    }
    grid.sync();
    const int fm = p.flags[0];
    const int im = p.flags[1];

    // ---- P1: degree + bounds + convert x->bf16 A (+stats0) + weight converts ----
    for (int e = gid; e < p.E; e += gstride) atomicAdd(&p.cnt[ldi(p.ei, p.E + e, im)], 1);
    for (int n = gid; n < p.N; n += gstride) {
        int b = ldi(p.batch, n, im);
        if (n == 0) {
            for (int g = 0; g <= b; ++g) p.bnd[g] = 0;
        } else {
            int bp = ldi(p.batch, n - 1, im);
            for (int g = bp + 1; g <= b; ++g) p.bnd[g] = n;
        }
        if (n == p.N - 1) {
            for (int g = b + 1; g <= 256; ++g) p.bnd[g] = p.N;
        }
    }
    {
        int np = p.N * 64;  // u32 pairs; gstride % 64 == 0 keeps feature pair fixed per thread
        float s0 = 0.f, s1 = 0.f, q0 = 0.f, q1 = 0.f;
        u32* A2 = (u32*)p.A;
        for (int j = gid; j < np; j += gstride) {
            float v0 = ldf(p.x, 2 * j, fm);
            float v1 = ldf(p.x, 2 * j + 1, fm);
            A2[j] = pack2(v0, v1);
            s0 += v0;
            q0 += v0 * v0;
            s1 += v1;
            q1 += v1 * v1;
        }
        shf2[t] = make_float2(s0, s1);
        __syncthreads();
        float* so = p.stats + (bid & 7) * 256;
        if (t < 64) {
            float a = 0.f, b = 0.f;
#pragma unroll
            for (int w = 0; w < 4; ++w) {
                float2 v = shf2[t + w * 64];
                a += v.x;
                b += v.y;
            }
            atomicAdd(&so[2 * t], a);
            atomicAdd(&so[2 * t + 1], b);
        }
        __syncthreads();
        shf2[t] = make_float2(q0, q1);
        __syncthreads();
        if (t < 64) {
            float a = 0.f, b = 0.f;
#pragma unroll
            for (int w = 0; w < 4; ++w) {
                float2 v = shf2[t + w * 64];
                a += v.x;
                b += v.y;
            }
            atomicAdd(&so[128 + 2 * t], a);
            atomicAdd(&so[128 + 2 * t + 1], b);
        }
        __syncthreads();
    }
    for (int i = gid; i < 16384; i += gstride) {
        int n = i >> 7, k = i & 127;
        p.Wtg[i] = f2b(ldf(p.gate_W1, k * 128 + n, fm));  // transpose
        p.fcWf[i] = ldf(p.fc_W, i, fm);
    }
    for (int i = gid; i < 1280; i += gstride) p.clsWf[i] = ldf(p.cls_W, i, fm);
    for (int i = gid; i < 128; i += gstride) {
        p.fcbf[i] = ldf(p.fc_b, i, fm);
        p.bias2g[i] = ldf(p.gate_b1, i, fm);
        p.gW2f[i] = ldf(p.gate_W2, i, fm);
    }
    for (int i = gid; i < 10; i += gstride) p.clsbf[i] = ldf(p.cls_b, i, fm);
    if (gid == 0) p.gb2f[0] = ldf(p.gate_b2, 0, fm);
    grid.sync();

    // ---- P2-P4: hierarchical exclusive scan cnt -> row_start ----
    for (int b = bid; b < p.NB; b += nb) {
        int base = b * 1024 + t * 4;
        int s = 0;
#pragma unroll
        for (int j = 0; j < 4; ++j) {
            int idx = base + j;
            if (idx < p.N) s += p.cnt[idx];
        }
        shi[t] = s;
        __syncthreads();
        for (int o = 128; o > 0; o >>= 1) {
            if (t < o) shi[t] += shi[t + o];
            __syncthreads();
        }
        if (t == 0) p.part[b] = shi[0];
        __syncthreads();
    }
    grid.sync();
    if (bid == 0) {
        int v = (t < p.NB) ? p.part[t] : 0;
        shi[t] = v;
        __syncthreads();
        for (int o = 1; o < 256; o <<= 1) {
            int add = (t >= o) ? shi[t - o] : 0;
            __syncthreads();
            shi[t] += add;
            __syncthreads();
        }
        if (t < p.NB) p.part[t] = shi[t] - v;
    }
    grid.sync();
    for (int b = bid; b < p.NB; b += nb) {
        int base = b * 1024 + t * 4;
        int v[4];
        int s = 0;
#pragma unroll
        for (int j = 0; j < 4; ++j) {
            int idx = base + j;
            v[j] = (idx < p.N) ? p.cnt[idx] : 0;
            s += v[j];
        }
        shi[t] = s;
        __syncthreads();
        for (int o = 1; o < 256; o <<= 1) {
            int add = (t >= o) ? shi[t - o] : 0;
            __syncthreads();
            shi[t] += add;
            __syncthreads();
        }
        int run = p.part[b] + shi[t] - s;
#pragma unroll
        for (int j = 0; j < 4; ++j) {
            int idx = base + j;
            run += v[j];
            if (idx < p.N) p.row_start[idx + 1] = run;
        }
        if (b == 0 && t == 0) p.row_start[0] = 0;
        __syncthreads();
    }
    grid.sync();

    // ---- P5: CSR fill ----
    for (int e = gid; e < p.E; e += gstride) {
        int s = ldi(p.ei, e, im);
        int d = ldi(p.ei, p.E + e, im);
        int pos = p.row_start[d] + atomicAdd(&p.fillc[d], 1);
        p.col_idx[pos] = s;
        p.coef[pos] = rsqrtf((float)p.cnt[s] + 1.0f) * rsqrtf((float)p.cnt[d] + 1.0f);
    }
    grid.sync();

    // ---- GCN layers ----
    const int mmt = (p.N + 63) / 64;
    const int atl = (p.N + 3) / 4;
    for (int l = 0; l < 4; ++l) {
        const void* W = l ? p.conv_W : p.conv_feat_W;
        const void* gg = l ? p.bn_conv_g : p.bn_feat_g;
        const void* be = l ? p.bn_conv_b : p.bn_feat_b;
        const void* bb = l ? p.conv_b : p.conv_feat_b;
        int woff = l ? (l - 1) * 16384 : 0;
        int poff = l ? (l - 1) * 128 : 0;
        const float* st = p.stats + (size_t)l * 2048;
        // wprep: fold BN into Wt (transposed bf16) + bias2
        for (int n = bid; n < 128; n += nb) {
            float contrib = 0.f;
            if (t < 128) {
                float ms = 0.f, qs = 0.f;
#pragma unroll
                for (int c = 0; c < 8; ++c) {
                    ms += st[c * 256 + t];
                    qs += st[c * 256 + 128 + t];
                }
                float m = ms / (float)p.N;
                float var = qs / (float)p.N - m * m;
                float rs = rsqrtf(var + EPSI);
                float sc = rs * ldf(gg, poff + t, fm);
                float sh = ldf(be, poff + t, fm) - m * sc;
                float w = ldf(W, woff + t * 128 + n, fm);
                p.Wt[n * 128 + t] = f2b(sc * w);
                contrib = sh * w;
            }
            red[t] = contrib;
            __syncthreads();
            for (int o = 128; o > 0; o >>= 1) {
                if (t < o) red[t] += red[t + o];
                __syncthreads();
            }
            if (t == 0) p.bias2[n] = red[0];
            __syncthreads();
        }
        grid.sync();
        // mfma GEMM
        for (int tile = bid; tile < mmt; tile += nb)
            mfma_tile(p.A, p.Wt, p.bias2, p.C, nullptr, nullptr, 0.f, p.N, 0, tile, t);
        grid.sync();
        // agg + register-accumulated BN stats for next layer
        {
            int wid = t >> 6, lane = t & 63;
            const u32* C2 = (const u32*)p.C;
            u32* A2 = (u32*)p.A;
            float sx = 0.f, sy = 0.f, qx = 0.f, qy = 0.f;
            for (int tile = bid; tile < atl; tile += nb) {
                int node = tile * 4 + wid;
                float ax = 0.f, ay = 0.f;
                if (node < p.N) {
                    float d2 = 1.0f / ((float)p.cnt[node] + 1.0f);
                    u32 selfw = C2[(size_t)node * 64 + lane];
                    ax = b2f((u16)selfw) * d2;
                    ay = b2f((u16)(selfw >> 16)) * d2;
                    int rs = p.row_start[node], re = p.row_start[node + 1];
                    int e = rs;
                    for (; e + 4 <= re; e += 4) {
                        int s0 = p.col_idx[e + 0], s1 = p.col_idx[e + 1];
                        int s2 = p.col_idx[e + 2], s3 = p.col_idx[e + 3];
                        float w0 = p.coef[e + 0], w1 = p.coef[e + 1];
                        float w2 = p.coef[e + 2], w3 = p.coef[e + 3];
                        u32 v0 = C2[(size_t)s0 * 64 + lane];
                        u32 v1 = C2[(size_t)s1 * 64 + lane];
                        u32 v2 = C2[(size_t)s2 * 64 + lane];
                        u32 v3 = C2[(size_t)s3 * 64 + lane];
                        ax += b2f((u16)v0) * w0 + b2f((u16)v1) * w1 + b2f((u16)v2) * w2 +
                              b2f((u16)v3) * w3;
                        ay += b2f((u16)(v0 >> 16)) * w0 + b2f((u16)(v1 >> 16)) * w1 +
                              b2f((u16)(v2 >> 16)) * w2 + b2f((u16)(v3 >> 16)) * w3;
                    }
                    for (; e < re; ++e) {
                        int s = p.col_idx[e];
                        float w = p.coef[e];
                        u32 v = C2[(size_t)s * 64 + lane];
                        ax += b2f((u16)v) * w;
                        ay += b2f((u16)(v >> 16)) * w;
                    }
                    int f = lane * 2;
                    ax = fmaxf(ax + ldf(bb, poff + f, fm), 0.0f);
                    ay = fmaxf(ay + ldf(bb, poff + f + 1, fm), 0.0f);
                    A2[(size_t)node * 64 + lane] = pack2(ax, ay);
                }
                sx += ax;
                sy += ay;
                qx += ax * ax;
                qy += ay * ay;
            }
            shf2[t] = make_float2(sx, sy);
            __syncthreads();
            float* so = p.stats + (size_t)(l + 1) * 2048 + (bid & 7) * 256;
            if (t < 64) {
                float a = 0.f, b = 0.f;
#pragma unroll
                for (int w = 0; w < 4; ++w) {
                    float2 v = shf2[t + w * 64];
                    a += v.x;
                    b += v.y;
                }
                atomicAdd(&so[2 * t], a);
                atomicAdd(&so[2 * t + 1], b);
            }
            __syncthreads();
            shf2[t] = make_float2(qx, qy);
            __syncthreads();
            if (t < 64) {
                float a = 0.f, b = 0.f;
#pragma unroll
                for (int w = 0; w < 4; ++w) {
                    float2 v = shf2[t + w * 64];
                    a += v.x;
                    b += v.y;
                }
                atomicAdd(&so[128 + 2 * t], a);
                atomicAdd(&so[128 + 2 * t + 1], b);
            }
            __syncthreads();
        }
        grid.sync();
    }

    // ---- gate head (fused relu(A@W1+b1)@W2+b2 -> sigmoid) ----
    {
        float gb2v = p.gb2f[0];
        for (int tile = bid; tile < mmt; tile += nb)
            mfma_tile(p.A, p.Wtg, p.bias2g, nullptr, p.gateb, p.gW2f, gb2v, p.N, 2, tile, t);
    }
    grid.sync();

    // ---- pool (+ BN stats over graphs for head BN) ----
    for (int g = bid; g < 256; g += nb) {
        int s = p.bnd[g], e = p.bnd[g + 1];
        int f = t & 127, half = t >> 7;
        float acc = 0.f;
        for (int r = s + half; r < e; r += 2)
            acc += b2f(p.A[(size_t)r * 128 + f]) * p.gateb[r];
        red[t] = acc;
        __syncthreads();
        if (t < 128) {
            float v = red[t] + red[t + 128];
            p.pooled[g * 128 + t] = v;
            float* so = p.statsP + (g & 7) * 256;
            atomicAdd(&so[t], v);
            atomicAdd(&so[128 + t], v * v);
        }
        __syncthreads();
    }
    grid.sync();

    // ---- head: inline BN + fc(relu) + cls + log_softmax ----
    if (t < 128) {
        float ms = 0.f, qs = 0.f;
#pragma unroll
        for (int c = 0; c < 8; ++c) {
            ms += p.statsP[c * 256 + t];
            qs += p.statsP[c * 256 + 128 + t];
        }
        float m = ms / 256.0f;
        float var = qs / 256.0f - m * m;
        float rs = rsqrtf(var + EPSI);
        float sc = rs * ldf(p.bn_fc_g, t, fm);
        scs[t] = sc;
        shs[t] = ldf(p.bn_fc_b, t, fm) - m * sc;
    }
    __syncthreads();
    for (int g = bid; g < 256; g += nb) {
        int j = t & 127, half = t >> 7;
        float acc = 0.f;
        int k0 = half * 64;
#pragma unroll 4
        for (int k = k0; k < k0 + 64; ++k) {
            float a = p.pooled[g * 128 + k] * scs[k] + shs[k];
            acc += a * p.fcWf[k * 128 + j];
        }
        red[t] = acc;
        __syncthreads();
        if (t < 128) fco[t] = fmaxf(red[t] + red[t + 128] + p.fcbf[t], 0.0f);
        __syncthreads();
        if (t < 10) {
            float a = p.clsbf[t];
#pragma unroll 4
            for (int k = 0; k < 128; ++k) a += fco[k] * p.clsWf[k * 10 + t];
            lg[t] = a;
        }
        __syncthreads();
        if (t == 0) {
            float mx = lg[0];
            for (int j2 = 1; j2 < 10; ++j2) mx = fmaxf(mx, lg[j2]);
            float se = 0.f;
            for (int j2 = 0; j2 < 10; ++j2) se += expf(lg[j2] - mx);
            redv[0] = mx;
            redv[1] = logf(se);
        }
        __syncthreads();
        if (t < 10) {
            float v = lg[t] - redv[0] - redv[1];
            if (fm == 1) ((u16*)p.out)[g * 10 + t] = f2b(v);
            else if (fm == 2) ((u16*)p.out)[g * 10 + t] = __half_as_ushort(__float2half(v));
            else ((float*)p.out)[g * 10 + t] = v;
        }
        __syncthreads();
    }
}

extern "C" void kernel_launch(void* const* d_in, const int* in_sizes, int n_in,
                              void* d_out, int out_size, void* d_ws, size_t ws_size,
                              hipStream_t stream) {
    const int N = in_sizes[2];
    const int E = in_sizes[1] / 2;
    const int NB = (N + 1023) / 1024;

    u32* ws = (u32*)d_ws;
    size_t off = 0;
    auto alloc = [&](size_t n) {
        size_t o = off;
        off += (n + 63) & ~(size_t)63;
        return o;
    };
    size_t o_cnt = alloc(N);
    size_t o_fill = alloc(N);
    size_t o_stats = alloc(5 * 2048);
    size_t o_statsP = alloc(2048);
    size_t zero_end = off;
    size_t o_flags = alloc(16);
    size_t o_part = alloc(256);
    size_t o_rs = alloc((size_t)N + 1);
    size_t o_col = alloc(E);
    size_t o_coef = alloc(E);
    size_t o_wt = alloc(128 * 128 / 2);
    size_t o_b2 = alloc(128);
    size_t o_wtg = alloc(128 * 128 / 2);
    size_t o_b2g = alloc(128);
    size_t o_fcW = alloc(16384);
    size_t o_fcb = alloc(128);
    size_t o_clsW = alloc(1280);
    size_t o_clsb = alloc(16);
    size_t o_gW2 = alloc(128);
    size_t o_gb2 = alloc(16);
    size_t o_gate = alloc(N);
    size_t o_bnd = alloc(257);
    size_t o_pool = alloc(256 * 128);
    size_t o_A = alloc((size_t)N * 64);
    size_t o_C = alloc((size_t)N * 64);
    (void)ws_size;
    (void)n_in;
    (void)out_size;

    MegaParams p;
    p.x = d_in[0];
    p.ei = d_in[1];
    p.batch = d_in[2];
    p.bn_feat_g = d_in[3];
    p.bn_feat_b = d_in[4];
    p.conv_feat_W = d_in[5];
    p.conv_feat_b = d_in[6];
    p.conv_W = d_in[7];
    p.conv_b = d_in[8];
    p.bn_conv_g = d_in[9];
    p.bn_conv_b = d_in[10];
    p.gate_W1 = d_in[11];
    p.gate_b1 = d_in[12];
    p.gate_W2 = d_in[13];
    p.gate_b2 = d_in[14];
    p.fc_W = d_in[15];
    p.fc_b = d_in[16];
    p.bn_fc_g = d_in[17];
    p.bn_fc_b = d_in[18];
    p.cls_W = d_in[19];
    p.cls_b = d_in[20];
    p.zbase = ws;
    p.flags = (int*)(ws + o_flags);
    p.cnt = (int*)(ws + o_cnt);
    p.fillc = (int*)(ws + o_fill);
    p.stats = (float*)(ws + o_stats);
    p.statsP = (float*)(ws + o_statsP);
    p.part = (int*)(ws + o_part);
    p.row_start = (int*)(ws + o_rs);
    p.col_idx = (int*)(ws + o_col);
    p.coef = (float*)(ws + o_coef);
    p.bnd = (int*)(ws + o_bnd);
    p.Wt = (u16*)(ws + o_wt);
    p.bias2 = (float*)(ws + o_b2);
    p.Wtg = (u16*)(ws + o_wtg);
    p.bias2g = (float*)(ws + o_b2g);
    p.fcWf = (float*)(ws + o_fcW);
    p.fcbf = (float*)(ws + o_fcb);
    p.clsWf = (float*)(ws + o_clsW);
    p.clsbf = (float*)(ws + o_clsb);
    p.gW2f = (float*)(ws + o_gW2);
    p.gb2f = (float*)(ws + o_gb2);
    p.gateb = (float*)(ws + o_gate);
    p.pooled = (float*)(ws + o_pool);
    p.A = (u16*)(ws + o_A);
    p.C = (u16*)(ws + o_C);
    p.out = d_out;
    p.nz = (int)zero_end;
    p.N = N;
    p.E = E;
    p.NB = NB;

    int dev = 0;
    hipGetDevice(&dev);
    int numCU = 256;
    hipDeviceGetAttribute(&numCU, hipDeviceAttributeMultiprocessorCount, dev);
    int maxB = 0;
    hipOccupancyMaxActiveBlocksPerMultiprocessor(&maxB, (const void*)mega_kernel, 256, 0);
    if (maxB < 1) maxB = 1;
    long long B = (long long)maxB * (long long)numCU;
    if (B > 2048) B = 2048;
    if (B < 1) B = 1;

    void* args[] = {(void*)&p};
    hipLaunchCooperativeKernel((const void*)mega_kernel, dim3((u32)B), dim3(256), args, 0,
                               stream);
}

// Round 8
// 534.684 us; speedup vs baseline: 3.5020x; 3.5020x over previous
//
#include <hip/hip_runtime.h>
#include <hip/hip_fp16.h>

typedef unsigned short u16;
typedef unsigned int u32;
typedef __attribute__((ext_vector_type(8))) short short8;
typedef __attribute__((ext_vector_type(4))) float floatx4;

#define EPSI 1e-5f

__device__ __forceinline__ float b2f(u16 h) { return __uint_as_float(((u32)h) << 16); }
__device__ __forceinline__ u16 f2b(float f) {
    u32 u = __float_as_uint(f);
    return (u16)((u + 0x7fffu + ((u >> 16) & 1u)) >> 16);
}
__device__ __forceinline__ u32 pack2(float a, float b) {
    return (u32)f2b(a) | ((u32)f2b(b) << 16);
}
// fm: 0 = f32, 1 = bf16, 2 = f16. Element-indexed, width-agnostic.
__device__ __forceinline__ float ldf(const void* p, int i, int fm) {
    if (fm == 1) return b2f(((const u16*)p)[i]);
    if (fm == 2) return __half2float(__ushort_as_half(((const u16*)p)[i]));
    return ((const float*)p)[i];
}
// im: 0 = int32, 1 = int64 (little-endian low word)
__device__ __forceinline__ int ldi(const void* p, int i, int im) {
    return im ? ((const int*)p)[2 * i] : ((const int*)p)[i];
}

// zero counters/stats; block0/t0 detects dtypes
__global__ void init_kernel(u32* zp, int nz, const void* ones, const void* ei, int* flags) {
    int i = blockIdx.x * 256 + threadIdx.x;
    if (i < nz) zp[i] = 0;
    if (blockIdx.x == 0 && threadIdx.x == 0) {
        u32 w = ((const u32*)ones)[0];
        int fm = 0;
        if (w == 0x3F803F80u) fm = 1;
        else if (w == 0x3C003C00u) fm = 2;
        const u32* e = (const u32*)ei;
        int all0 = 1;
        for (int k = 0; k < 16; ++k)
            if (e[2 * k + 1] != 0u) all0 = 0;
        flags[0] = fm;
        flags[1] = all0;
    }
}

// degree histogram + graph bounds (independent jobs, same launch)
__global__ void deg_bounds_kernel(const void* __restrict__ ei, int* __restrict__ cnt, int E,
                                  const void* __restrict__ batch, int* __restrict__ bounds,
                                  int N, const int* __restrict__ flags) {
    int im = flags[1];
    int g = blockIdx.x * 256 + threadIdx.x;
    if (g < E) atomicAdd(&cnt[ldi(ei, E + g, im)], 1);
    if (g < N) {
        int b = ldi(batch, g, im);
        if (g == 0) {
            for (int q = 0; q <= b; ++q) bounds[q] = 0;
        } else {
            int bp = ldi(batch, g - 1, im);
            for (int q = bp + 1; q <= b; ++q) bounds[q] = g;
        }
        if (g == N - 1) {
            for (int q = b + 1; q <= 256; ++q) bounds[q] = N;
        }
    }
}

// ---- hierarchical scan ----
__global__ void scan_part_kernel(const int* __restrict__ cnt, int* __restrict__ part, int n) {
    int b = blockIdx.x, t = threadIdx.x;
    int base = b * 1024 + t * 4;
    int s = 0;
#pragma unroll
    for (int j = 0; j < 4; ++j) {
        int idx = base + j;
        if (idx < n) s += cnt[idx];
    }
    __shared__ int sh[256];
    sh[t] = s;
    __syncthreads();
    for (int o = 128; o > 0; o >>= 1) {
        if (t < o) sh[t] += sh[t + o];
        __syncthreads();
    }
    if (t == 0) part[b] = sh[0];
}

__global__ void scan_top_kernel(int* __restrict__ part, int nb) {
    __shared__ int sh[256];
    int t = threadIdx.x;
    int v = (t < nb) ? part[t] : 0;
    sh[t] = v;
    __syncthreads();
    for (int o = 1; o < 256; o <<= 1) {
        int add = (t >= o) ? sh[t - o] : 0;
        __syncthreads();
        sh[t] += add;
        __syncthreads();
    }
    if (t < nb) part[t] = sh[t] - v;
}

__global__ void scan_local_kernel(const int* __restrict__ cnt, const int* __restrict__ part,
                                  int* __restrict__ row_start, int n) {
    int b = blockIdx.x, t = threadIdx.x;
    int base = b * 1024 + t * 4;
    int v[4];
    int s = 0;
#pragma unroll
    for (int j = 0; j < 4; ++j) {
        int idx = base + j;
        v[j] = (idx < n) ? cnt[idx] : 0;
        s += v[j];
    }
    __shared__ int sh[256];
    sh[t] = s;
    __syncthreads();
    for (int o = 1; o < 256; o <<= 1) {
        int add = (t >= o) ? sh[t - o] : 0;
        __syncthreads();
        sh[t] += add;
        __syncthreads();
    }
    int run = part[b] + sh[t] - s;
#pragma unroll
    for (int j = 0; j < 4; ++j) {
        int idx = base + j;
        run += v[j];
        if (idx < n) row_start[idx + 1] = run;
    }
    if (b == 0 && t == 0) row_start[0] = 0;
}

__global__ void fill_kernel(const void* __restrict__ ei, const int* __restrict__ row_start,
                            int* __restrict__ fill_cnt, const int* __restrict__ cnt,
                            int* __restrict__ col_idx, float* __restrict__ coef, int E,
                            const int* __restrict__ flags) {
    int im = flags[1];
    int e = blockIdx.x * 256 + threadIdx.x;
    if (e < E) {
        int s = ldi(ei, e, im);
        int d = ldi(ei, E + e, im);
        int p = row_start[d] + atomicAdd(&fill_cnt[d], 1);
        col_idx[p] = s;
        coef[p] = rsqrtf((float)cnt[s] + 1.0f) * rsqrtf((float)cnt[d] + 1.0f);
    }
}

// Preprocess mega-grid:
//  bid <512: convert x -> bf16 A (+ stats0, 8 slot copies)
//  512..639: gate wprep (Wtg = gate_W1^T bf16; bias2g = gate_b1 f32)
//  640..703: LDS-tiled transpose of 4 conv W matrices -> WTf f32 [mat][n][k]
//  704..711: fc_W -> f32
//  712:      cls_W/cls_b/fc_b/gate_W2/gate_b2 -> f32
__global__ void prep_kernel(const void* __restrict__ x, u32* __restrict__ A2, int N,
                            float* __restrict__ stats0, const void* __restrict__ gW1,
                            const void* __restrict__ gb1, u16* __restrict__ Wtg,
                            float* __restrict__ bias2g, const void* __restrict__ cfW,
                            const void* __restrict__ cW, float* __restrict__ WTf,
                            const void* __restrict__ fcW, float* __restrict__ fcWf,
                            const void* __restrict__ clsW, float* __restrict__ clsWf,
                            const void* __restrict__ fcb, float* __restrict__ fcbf,
                            const void* __restrict__ clsb, float* __restrict__ clsbf,
                            const void* __restrict__ gW2, float* __restrict__ gW2f,
                            const void* __restrict__ gb2, float* __restrict__ gb2f,
                            const int* __restrict__ flags) {
    int fm = flags[0];
    int bid = blockIdx.x, t = threadIdx.x;
    if (bid < 512) {
        int np = N * 64;
        float s0 = 0.f, s1 = 0.f, q0 = 0.f, q1 = 0.f;
        if (fm == 1) {
            const u32* xs = (const u32*)x;
            for (int j = bid * 256 + t; j < np; j += 512 * 256) {
                u32 w = xs[j];
                A2[j] = w;
                float v0 = b2f((u16)w), v1 = b2f((u16)(w >> 16));
                s0 += v0;
                q0 += v0 * v0;
                s1 += v1;
                q1 += v1 * v1;
            }
        } else {
            for (int j = bid * 256 + t; j < np; j += 512 * 256) {
                float v0 = ldf(x, 2 * j, fm);
                float v1 = ldf(x, 2 * j + 1, fm);
                A2[j] = pack2(v0, v1);
                s0 += v0;
                q0 += v0 * v0;
                s1 += v1;
                q1 += v1 * v1;
            }
        }
        __shared__ float2 sh[256];
        sh[t] = make_float2(s0, s1);
        __syncthreads();
        float* so = stats0 + (bid & 7) * 256;
        if (t < 64) {
            float a = 0.f, b = 0.f;
#pragma unroll
            for (int w = 0; w < 4; ++w) {
                float2 v = sh[t + w * 64];
                a += v.x;
                b += v.y;
            }
            atomicAdd(&so[2 * t], a);
            atomicAdd(&so[2 * t + 1], b);
        }
        __syncthreads();
        sh[t] = make_float2(q0, q1);
        __syncthreads();
        if (t < 64) {
            float a = 0.f, b = 0.f;
#pragma unroll
            for (int w = 0; w < 4; ++w) {
                float2 v = sh[t + w * 64];
                a += v.x;
                b += v.y;
            }
            atomicAdd(&so[128 + 2 * t], a);
            atomicAdd(&so[128 + 2 * t + 1], b);
        }
    } else if (bid < 640) {
        int n = bid - 512;
        if (t < 128) Wtg[n * 128 + t] = f2b(ldf(gW1, t * 128 + n, fm));
        if (t == 0) bias2g[n] = ldf(gb1, n, fm);
    } else if (bid < 704) {
        int task = bid - 640;
        int mat = task >> 4, tile = task & 15;
        int tr = (tile >> 2) * 32, tc = (tile & 3) * 32;
        const void* src = mat == 0 ? cfW : cW;
        int soff = mat == 0 ? 0 : (mat - 1) * 16384;
        __shared__ float tb[32][33];
#pragma unroll
        for (int i = 0; i < 4; ++i) {
            int o = t * 4 + i;
            int r = o >> 5, c = o & 31;
            tb[r][c] = ldf(src, soff + (tr + r) * 128 + tc + c, fm);
        }
        __syncthreads();
        float* dst = WTf + mat * 16384;
#pragma unroll
        for (int i = 0; i < 4; ++i) {
            int o = t * 4 + i;
            int nr = o >> 5, kc = o & 31;
            dst[(tc + nr) * 128 + tr + kc] = tb[kc][nr];
        }
    } else if (bid < 712) {
        int base = (bid - 704) * 2048;
        for (int i = t; i < 2048; i += 256) fcWf[base + i] = ldf(fcW, base + i, fm);
    } else {
        for (int i = t; i < 1280; i += 256) clsWf[i] = ldf(clsW, i, fm);
        if (t < 128) {
            fcbf[t] = ldf(fcb, t, fm);
            gW2f[t] = ldf(gW2, t, fm);
        }
        if (t < 10) clsbf[t] = ldf(clsb, t, fm);
        if (t == 0) gb2f[0] = ldf(gb2, 0, fm);
    }
}

// Fold BN into weights using transposed f32 WTf (coalesced reads)
__global__ void wprep_kernel(const float* __restrict__ stats, const void* __restrict__ bng,
                             const void* __restrict__ bnb, int poff,
                             const float* __restrict__ WTf, int woff, u16* __restrict__ Wt,
                             float* __restrict__ bias2, int N, const int* __restrict__ flags) {
    int fm = flags[0];
    int n = blockIdx.x, k = threadIdx.x;
    float ms = 0.f, qs = 0.f;
#pragma unroll
    for (int c = 0; c < 8; ++c) {
        ms += stats[c * 256 + k];
        qs += stats[c * 256 + 128 + k];
    }
    float m = ms / (float)N;
    float var = qs / (float)N - m * m;
    float rs = rsqrtf(var + EPSI);
    float sc = rs * ldf(bng, poff + k, fm);
    float sh = ldf(bnb, poff + k, fm) - m * sc;
    float w = WTf[woff + n * 128 + k];
    Wt[n * 128 + k] = f2b(sc * w);
    __shared__ float red[128];
    red[k] = sh * w;
    __syncthreads();
    for (int o = 64; o > 0; o >>= 1) {
        if (k < o) red[k] += red[k + o];
        __syncthreads();
    }
    if (k == 0) bias2[n] = red[0];
}

// MFMA GEMM: bf16 A [N,128] @ W' + bias2.
// mode 0: store C (bf16). mode 2: fused gate head (gate[r] = sigmoid(relu(h)·W2 + b2)).
__global__ __launch_bounds__(256) void mfma_mm_kernel(
    const u16* __restrict__ A, const u16* __restrict__ Wt, const float* __restrict__ bias2,
    u16* __restrict__ C, float* __restrict__ gate, const float* __restrict__ gW2f,
    const float* __restrict__ gb2f, int N, int mode) {
    int t = threadIdx.x;
    int wid = t >> 6, lane = t & 63;
    int m16 = lane & 15, q = lane >> 4;
    int row0 = blockIdx.x * 64 + wid * 16;
    if (row0 >= N) return;
    int arow = row0 + m16;
    floatx4 acc[8];
#pragma unroll
    for (int i = 0; i < 8; ++i) acc[i] = (floatx4){0.f, 0.f, 0.f, 0.f};
#pragma unroll
    for (int kc = 0; kc < 4; ++kc) {
        short8 af;
        if (arow < N) {
            af = *(const short8*)&A[(size_t)arow * 128 + kc * 32 + q * 8];
        } else {
#pragma unroll
            for (int j = 0; j < 8; ++j) af[j] = 0;
        }
#pragma unroll
        for (int nt = 0; nt < 8; ++nt) {
            short8 bf = *(const short8*)&Wt[(nt * 16 + m16) * 128 + kc * 32 + q * 8];
            acc[nt] = __builtin_amdgcn_mfma_f32_16x16x32_bf16(af, bf, acc[nt], 0, 0, 0);
        }
    }
    if (mode == 0) {
#pragma unroll
        for (int nt = 0; nt < 8; ++nt) {
            float b2v = bias2[nt * 16 + m16];
#pragma unroll
            for (int reg = 0; reg < 4; ++reg) {
                int r = row0 + q * 4 + reg;
                if (r < N) C[(size_t)r * 128 + nt * 16 + m16] = f2b(acc[nt][reg] + b2v);
            }
        }
    } else {
        float p[4] = {0.f, 0.f, 0.f, 0.f};
#pragma unroll
        for (int nt = 0; nt < 8; ++nt) {
            float b2v = bias2[nt * 16 + m16];
            float w2v = gW2f[nt * 16 + m16];
#pragma unroll
            for (int reg = 0; reg < 4; ++reg)
                p[reg] += fmaxf(acc[nt][reg] + b2v, 0.0f) * w2v;
        }
        float gb = gb2f[0];
#pragma unroll
        for (int reg = 0; reg < 4; ++reg) {
            float v = p[reg];
            v += __shfl_xor(v, 1);
            v += __shfl_xor(v, 2);
            v += __shfl_xor(v, 4);
            v += __shfl_xor(v, 8);
            if (m16 == 0) {
                int r = row0 + q * 4 + reg;
                if (r < N) gate[r] = 1.0f / (1.0f + expf(-(v + gb)));
            }
        }
    }
}

// gather aggregation over bf16 C rows + fused BN-stats for the NEXT layer.
// 16 nodes/block; edge loop unrolled x8/x4 for memory-level parallelism.
__global__ __launch_bounds__(1024) void agg_kernel(
    const u32* __restrict__ C2, const int* __restrict__ row_start,
    const int* __restrict__ col_idx, const float* __restrict__ coef,
    const int* __restrict__ cnt, const void* __restrict__ bias, int boff,
    u32* __restrict__ A2, float* __restrict__ statsOut, int N,
    const int* __restrict__ flags) {
    int fm = flags[0];
    int t = threadIdx.x;
    int wid = t >> 6, lane = t & 63;
    int node = blockIdx.x * 16 + wid;
    float ax = 0.f, ay = 0.f;
    if (node < N) {
        float d2 = 1.0f / ((float)cnt[node] + 1.0f);
        u32 selfw = C2[(size_t)node * 64 + lane];
        ax = b2f((u16)selfw) * d2;
        ay = b2f((u16)(selfw >> 16)) * d2;
        int rs = row_start[node], re = row_start[node + 1];
        int e = rs;
        for (; e + 8 <= re; e += 8) {
            int si[8];
            float wi[8];
            u32 vi[8];
#pragma unroll
            for (int j = 0; j < 8; ++j) {
                si[j] = col_idx[e + j];
                wi[j] = coef[e + j];
            }
#pragma unroll
            for (int j = 0; j < 8; ++j) vi[j] = C2[(size_t)si[j] * 64 + lane];
#pragma unroll
            for (int j = 0; j < 8; ++j) {
                ax += b2f((u16)vi[j]) * wi[j];
                ay += b2f((u16)(vi[j] >> 16)) * wi[j];
            }
        }
        for (; e + 4 <= re; e += 4) {
            int s0 = col_idx[e + 0], s1 = col_idx[e + 1];
            int s2 = col_idx[e + 2], s3 = col_idx[e + 3];
            float w0 = coef[e + 0], w1 = coef[e + 1];
            float w2 = coef[e + 2], w3 = coef[e + 3];
            u32 v0 = C2[(size_t)s0 * 64 + lane];
            u32 v1 = C2[(size_t)s1 * 64 + lane];
            u32 v2 = C2[(size_t)s2 * 64 + lane];
            u32 v3 = C2[(size_t)s3 * 64 + lane];
            ax += b2f((u16)v0) * w0 + b2f((u16)v1) * w1 + b2f((u16)v2) * w2 + b2f((u16)v3) * w3;
            ay += b2f((u16)(v0 >> 16)) * w0 + b2f((u16)(v1 >> 16)) * w1 +
                  b2f((u16)(v2 >> 16)) * w2 + b2f((u16)(v3 >> 16)) * w3;
        }
        for (; e < re; ++e) {
            int s = col_idx[e];
            float w = coef[e];
            u32 v = C2[(size_t)s * 64 + lane];
            ax += b2f((u16)v) * w;
            ay += b2f((u16)(v >> 16)) * w;
        }
        int f = lane * 2;
        ax = fmaxf(ax + ldf(bias, boff + f, fm), 0.0f);
        ay = fmaxf(ay + ldf(bias, boff + f + 1, fm), 0.0f);
        A2[(size_t)node * 64 + lane] = pack2(ax, ay);
    }
    __shared__ float2 sh[1024];
    sh[t] = make_float2(ax, ay);
    __syncthreads();
    float* so = statsOut + (blockIdx.x & 7) * 256;
    if (t < 64) {
        float a = 0.f, b = 0.f;
#pragma unroll
        for (int w = 0; w < 16; ++w) {
            float2 v = sh[t + w * 64];
            a += v.x;
            b += v.y;
        }
        atomicAdd(&so[2 * t], a);
        atomicAdd(&so[2 * t + 1], b);
    }
    __syncthreads();
    sh[t] = make_float2(ax * ax, ay * ay);
    __syncthreads();
    if (t < 64) {
        float a = 0.f, b = 0.f;
#pragma unroll
        for (int w = 0; w < 16; ++w) {
            float2 v = sh[t + w * 64];
            a += v.x;
            b += v.y;
        }
        atomicAdd(&so[128 + 2 * t], a);
        atomicAdd(&so[128 + 2 * t + 1], b);
    }
}

// pooled[g,:] = sum_{nodes of g} A[n,:]*gate[n]; accumulates head-BN stats (8 slot copies)
__global__ void pool_kernel(const u16* __restrict__ A, const float* __restrict__ gate,
                            const int* __restrict__ bounds, float* __restrict__ pooled,
                            float* __restrict__ statsP) {
    int g = blockIdx.x;
    int t = threadIdx.x;
    int f = t & 127, half = t >> 7;
    int s = bounds[g], e = bounds[g + 1];
    float acc = 0.f;
    for (int r = s + half; r < e; r += 2) acc += b2f(A[(size_t)r * 128 + f]) * gate[r];
    __shared__ float sh[256];
    sh[t] = acc;
    __syncthreads();
    if (t < 128) {
        float v = sh[t] + sh[t + 128];
        pooled[g * 128 + t] = v;
        float* so = statsP + (g & 7) * 256;
        atomicAdd(&so[t], v);
        atomicAdd(&so[128 + t], v * v);
    }
}

// head: inline BN (from statsP) + fc(relu) + cls + log_softmax. One block per graph.
__global__ __launch_bounds__(256) void fc_cls_kernel(
    const float* __restrict__ pooled, const float* __restrict__ statsP,
    const void* __restrict__ bng, const void* __restrict__ bnb,
    const float* __restrict__ fcWf, const float* __restrict__ fcbf,
    const float* __restrict__ clsWf, const float* __restrict__ clsbf, void* __restrict__ out,
    const int* __restrict__ flags) {
    int fm = flags[0];
    int g = blockIdx.x, t = threadIdx.x;
    __shared__ float pv[128];
    __shared__ float red[256];
    __shared__ float fco[128];
    __shared__ float lg[10];
    __shared__ float redv[2];
    if (t < 128) {
        float ms = 0.f, qs = 0.f;
#pragma unroll
        for (int c = 0; c < 8; ++c) {
            ms += statsP[c * 256 + t];
            qs += statsP[c * 256 + 128 + t];
        }
        float m = ms / 256.0f;
        float var = qs / 256.0f - m * m;
        float rs = rsqrtf(var + EPSI);
        float sc = rs * ldf(bng, t, fm);
        pv[t] = pooled[g * 128 + t] * sc + (ldf(bnb, t, fm) - m * sc);
    }
    __syncthreads();
    {
        int j = t & 127, half = t >> 7;
        float acc = 0.f;
        int k0 = half * 64;
#pragma unroll 8
        for (int k = k0; k < k0 + 64; ++k) acc += pv[k] * fcWf[k * 128 + j];
        red[t] = acc;
    }
    __syncthreads();
    if (t < 128) fco[t] = fmaxf(red[t] + red[t + 128] + fcbf[t], 0.0f);
    __syncthreads();
    if (t < 10) {
        float a = clsbf[t];
#pragma unroll 8
        for (int k = 0; k < 128; ++k) a += fco[k] * clsWf[k * 10 + t];
        lg[t] = a;
    }
    __syncthreads();
    if (t == 0) {
        float mx = lg[0];
        for (int j = 1; j < 10; ++j) mx = fmaxf(mx, lg[j]);
        float se = 0.f;
        for (int j = 0; j < 10; ++j) se += expf(lg[j] - mx);
        redv[0] = mx;
        redv[1] = logf(se);
    }
    __syncthreads();
    if (t < 10) {
        float v = lg[t] - redv[0] - redv[1];
        if (fm == 1) ((u16*)out)[g * 10 + t] = f2b(v);
        else if (fm == 2) ((u16*)out)[g * 10 + t] = __half_as_ushort(__float2half(v));
        else ((float*)out)[g * 10 + t] = v;
    }
}

extern "C" void kernel_launch(void* const* d_in, const int* in_sizes, int n_in,
                              void* d_out, int out_size, void* d_ws, size_t ws_size,
                              hipStream_t stream) {
    const void* x = d_in[0];
    const void* ei = d_in[1];
    const void* batch = d_in[2];
    const void* bn_feat_g = d_in[3];
    const void* bn_feat_b = d_in[4];
    const void* conv_feat_W = d_in[5];
    const void* conv_feat_b = d_in[6];
    const void* conv_W = d_in[7];
    const void* conv_b = d_in[8];
    const void* bn_conv_g = d_in[9];
    const void* bn_conv_b = d_in[10];
    const void* gate_W1 = d_in[11];
    const void* gate_b1 = d_in[12];
    const void* gate_W2 = d_in[13];
    const void* gate_b2 = d_in[14];
    const void* fc_W = d_in[15];
    const void* fc_b = d_in[16];
    const void* bn_fc_g = d_in[17];
    const void* bn_fc_b = d_in[18];
    const void* cls_W = d_in[19];
    const void* cls_b = d_in[20];

    const int N = in_sizes[2];
    const int E = in_sizes[1] / 2;
    const int NB = (N + 1023) / 1024;

    u32* ws = (u32*)d_ws;
    size_t off = 0;
    auto alloc = [&](size_t n) {
        size_t o = off;
        off += (n + 63) & ~(size_t)63;
        return o;
    };
    size_t o_cnt = alloc(N);
    size_t o_fill = alloc(N);
    size_t o_stats = alloc(5 * 2048);
    size_t o_statsP = alloc(2048);
    size_t zero_end = off;
    size_t o_flags = alloc(16);
    size_t o_part = alloc(256);
    size_t o_rs = alloc((size_t)N + 1);
    size_t o_col = alloc(E);
    size_t o_coef = alloc(E);
    size_t o_wt = alloc(128 * 128 / 2);
    size_t o_b2 = alloc(128);
    size_t o_wtg = alloc(128 * 128 / 2);
    size_t o_b2g = alloc(128);
    size_t o_WTf = alloc(4 * 16384);
    size_t o_fcW = alloc(16384);
    size_t o_fcb = alloc(128);
    size_t o_clsW = alloc(1280);
    size_t o_clsb = alloc(16);
    size_t o_gW2 = alloc(128);
    size_t o_gb2 = alloc(16);
    size_t o_gate = alloc(N);
    size_t o_bnd = alloc(257);
    size_t o_pool = alloc(256 * 128);
    size_t o_A = alloc((size_t)N * 64);
    size_t o_C = alloc((size_t)N * 64);
    (void)ws_size;
    (void)n_in;
    (void)out_size;

    int* cnt = (int*)(ws + o_cnt);
    int* fillc = (int*)(ws + o_fill);
    float* stats = (float*)(ws + o_stats);
    float* statsP = (float*)(ws + o_statsP);
    int* flags = (int*)(ws + o_flags);
    int* part = (int*)(ws + o_part);
    int* row_start = (int*)(ws + o_rs);
    int* col_idx = (int*)(ws + o_col);
    float* coef = (float*)(ws + o_coef);
    u16* Wt = (u16*)(ws + o_wt);
    float* bias2 = (float*)(ws + o_b2);
    u16* Wtg = (u16*)(ws + o_wtg);
    float* bias2g = (float*)(ws + o_b2g);
    float* WTf = (float*)(ws + o_WTf);
    float* fcWf = (float*)(ws + o_fcW);
    float* fcbf = (float*)(ws + o_fcb);
    float* clsWf = (float*)(ws + o_clsW);
    float* clsbf = (float*)(ws + o_clsb);
    float* gW2f = (float*)(ws + o_gW2);
    float* gb2f = (float*)(ws + o_gb2);
    float* gateb = (float*)(ws + o_gate);
    int* bnd = (int*)(ws + o_bnd);
    float* pooled = (float*)(ws + o_pool);
    u16* A = (u16*)(ws + o_A);
    u16* C = (u16*)(ws + o_C);

    int nz = (int)zero_end;
    init_kernel<<<(nz + 255) / 256, 256, 0, stream>>>(ws, nz, bn_feat_g, ei, flags);
    deg_bounds_kernel<<<(E + 255) / 256, 256, 0, stream>>>(ei, cnt, E, batch, bnd, N, flags);
    scan_part_kernel<<<NB, 256, 0, stream>>>(cnt, part, N);
    scan_top_kernel<<<1, 256, 0, stream>>>(part, NB);
    scan_local_kernel<<<NB, 256, 0, stream>>>(cnt, part, row_start, N);
    fill_kernel<<<(E + 255) / 256, 256, 0, stream>>>(ei, row_start, fillc, cnt, col_idx, coef,
                                                     E, flags);
    prep_kernel<<<713, 256, 0, stream>>>(x, (u32*)A, N, stats, gate_W1, gate_b1, Wtg, bias2g,
                                         conv_feat_W, conv_W, WTf, fc_W, fcWf, cls_W, clsWf,
                                         fc_b, fcbf, cls_b, clsbf, gate_W2, gW2f, gate_b2, gb2f,
                                         flags);

    int mmgrid = (N + 63) / 64;
    int agggrid = (N + 15) / 16;
    for (int l = 0; l < 4; ++l) {
        const void *bb, *gg, *be;
        int poff = 0;
        if (l == 0) {
            bb = conv_feat_b; gg = bn_feat_g; be = bn_feat_b;
        } else {
            bb = conv_b; gg = bn_conv_g; be = bn_conv_b;
            poff = (l - 1) * 128;
        }
        wprep_kernel<<<128, 128, 0, stream>>>(stats + (size_t)l * 2048, gg, be, poff, WTf,
                                              l * 16384, Wt, bias2, N, flags);
        mfma_mm_kernel<<<mmgrid, 256, 0, stream>>>(A, Wt, bias2, C, nullptr, nullptr, nullptr,
                                                   N, 0);
        agg_kernel<<<agggrid, 1024, 0, stream>>>((const u32*)C, row_start, col_idx, coef, cnt,
                                                 bb, poff, (u32*)A,
                                                 stats + (size_t)(l + 1) * 2048, N, flags);
    }

    mfma_mm_kernel<<<mmgrid, 256, 0, stream>>>(A, Wtg, bias2g, nullptr, gateb, gW2f, gb2f, N, 2);
    pool_kernel<<<256, 256, 0, stream>>>(A, gateb, bnd, pooled, statsP);
    fc_cls_kernel<<<256, 256, 0, stream>>>(pooled, statsP, bn_fc_g, bn_fc_b, fcWf, fcbf, clsWf,
                                           clsbf, d_out, flags);
}